// Round 12
// baseline (124.146 us; speedup 1.0000x reference)
//
#include <hip/hip_runtime.h>
#include <math.h>

#define NOBS 7
#define PI_F 3.14159265358979f

typedef float v2f __attribute__((ext_vector_type(2)));

// ---- Layout (round-8/11 structure) ----
// Block = 512 threads = 8 waves. Wave wv = h*4 + s : s = ancilla value (0..3),
// h = wire-6 value (0..1). Each wave holds 128 main-register amplitudes:
// main index m (8 bits, wire w -> bit 7-w) = (lane<<2) | (h<<1) | r,
// lane bits = wires 0..5 (lane bit 5-w), h = wire6, r (reg pair, v2f) = wire7.
// State per lane: vr = (r0,r1) re, vi = (i0,i1) im — packed fp32 (v_pk_*).

// ---- VALU-only cross-lane xor exchange ----
template<int LM>
__device__ __forceinline__ float lane_partner(float x) {
  if constexpr (LM == 1) {
    return __int_as_float(__builtin_amdgcn_mov_dpp(__float_as_int(x), 0xB1, 0xF, 0xF, true));
  } else if constexpr (LM == 2) {
    return __int_as_float(__builtin_amdgcn_mov_dpp(__float_as_int(x), 0x4E, 0xF, 0xF, true));
  } else if constexpr (LM == 4) {
    int a = __builtin_amdgcn_mov_dpp(__float_as_int(x), 0x1B, 0xF, 0xF, true);   // xor3
    return __int_as_float(__builtin_amdgcn_mov_dpp(a, 0x141, 0xF, 0xF, true));   // xor7 -> net xor4
  } else if constexpr (LM == 8) {
    int a = __builtin_amdgcn_mov_dpp(__float_as_int(x), 0x141, 0xF, 0xF, true);  // xor7
    return __int_as_float(__builtin_amdgcn_mov_dpp(a, 0x140, 0xF, 0xF, true));   // xor15 -> net xor8
  } else if constexpr (LM == 16) {
#if __has_builtin(__builtin_amdgcn_permlane16_swap)
    unsigned xu = __float_as_uint(x);
    auto r = __builtin_amdgcn_permlane16_swap(xu, xu, false, false);
    return (__uint_as_float(r[0]) + __uint_as_float(r[1])) - x;
#else
    return __shfl_xor(x, 16, 64);
#endif
  } else {
#if __has_builtin(__builtin_amdgcn_permlane32_swap)
    unsigned xu = __float_as_uint(x);
    auto r = __builtin_amdgcn_permlane32_swap(xu, xu, false, false);
    return (__uint_as_float(r[0]) + __uint_as_float(r[1])) - x;
#else
    return __shfl_xor(x, 32, 64);
#endif
  }
}

template<int LM>
__device__ __forceinline__ v2f lane_partner2(v2f x) {
  v2f p;
  p.x = lane_partner<LM>(x.x);
  p.y = lane_partner<LM>(x.y);
  return p;
}

template<int LM>
__device__ __forceinline__ float xor_sum(float x) {
  if constexpr (LM == 16) {
#if __has_builtin(__builtin_amdgcn_permlane16_swap)
    unsigned xu = __float_as_uint(x);
    auto r = __builtin_amdgcn_permlane16_swap(xu, xu, false, false);
    return __uint_as_float(r[0]) + __uint_as_float(r[1]);
#else
    return x + __shfl_xor(x, 16, 64);
#endif
  } else if constexpr (LM == 32) {
#if __has_builtin(__builtin_amdgcn_permlane32_swap)
    unsigned xu = __float_as_uint(x);
    auto r = __builtin_amdgcn_permlane32_swap(xu, xu, false, false);
    return __uint_as_float(r[0]) + __uint_as_float(r[1]);
#else
    return x + __shfl_xor(x, 32, 64);
#endif
  } else {
    return x + lane_partner<LM>(x);
  }
}

__device__ __forceinline__ float rdlane(float v, int idx) {
  return __int_as_float(__builtin_amdgcn_readlane(__float_as_int(v), idx));
}

__device__ __forceinline__ float2 cmul(float2 a, float2 b) {
  return make_float2(a.x*b.x - a.y*b.y, a.x*b.y + a.y*b.x);
}
__device__ __forceinline__ float2 cmulc(float2 a, float2 b) {  // a * conj(b)
  return make_float2(a.x*b.x + a.y*b.y, a.y*b.x - a.x*b.y);
}
__device__ __forceinline__ float2 cadd(float2 a, float2 b) {
  return make_float2(a.x + b.x, a.y + b.y);
}

struct S4 { float r0, r1, i0, i1; };

// exchange with sibling wave (wv^4); one barrier; parity = site&1
__device__ __forceinline__ float4 wexch(int site, int wv, int lane,
                                        v2f vr, v2f vi) {
  extern __shared__ float4 dxw[];   // 2 * 512 entries (16 KB dynamic)
  float4* buf = dxw + (site & 1) * 512;
  buf[wv * 64 + lane] = make_float4(vr.x, vr.y, vi.x, vi.y);
  __syncthreads();
  return buf[(wv ^ 4) * 64 + lane];
}

// ---------------- gate helpers (v2f = 2 amps/lane, packed fp32) ----------------

template<int W>
__device__ __forceinline__ void ry_lane_g(v2f& vr, v2f& vi, int lane,
                                          float ct, float st, int idx, float sg) {
  float c = rdlane(ct, idx), s = sg * rdlane(st, idx);
  constexpr int LM = 1 << (5 - W);
  const float ls = (lane & LM) ? s : -s;
  v2f pr = lane_partner2<LM>(vr);
  v2f pi = lane_partner2<LM>(vi);
  vr = c*vr + ls*pr;
  vi = c*vi + ls*pi;
}

__device__ __forceinline__ void ry_wave6_g(v2f& vr, v2f& vi, int wv, int lane, int h,
                                           float ct, float st, int idx, float sg, int site) {
  float c = rdlane(ct, idx), s = sg * rdlane(st, idx);
  float4 P = wexch(site, wv, lane, vr, vi);
  const float ls = h ? s : -s;
  v2f Pr = {P.x, P.y}, Pi = {P.z, P.w};
  vr = c*vr + ls*Pr;
  vi = c*vi + ls*Pi;
}

__device__ __forceinline__ void ry_reg7_g(v2f& vr, v2f& vi,
                                          float ct, float st, int idx, float sg) {
  float c = rdlane(ct, idx), s = sg * rdlane(st, idx);
  float a0 = vr.x, a1 = vr.y;
  vr.x = c*a0 - s*a1;  vr.y = s*a0 + c*a1;
  float b0 = vi.x, b1 = vi.y;
  vi.x = c*b0 - s*b1;  vi.y = s*b0 + c*b1;
}

template<int C, int T>
__device__ __forceinline__ void crx_ll_g(v2f& vr, v2f& vi, int lane,
                                         float ct, float st, int idx, float sg) {
  float c = rdlane(ct, idx), s = sg * rdlane(st, idx);
  constexpr int LC = 1 << (5 - C), LT = 1 << (5 - T);
  const bool act = (lane & LC) != 0;
  const float cp = act ? c : 1.f, sp = act ? s : 0.f;
  v2f pr = lane_partner2<LT>(vr);
  v2f pi = lane_partner2<LT>(vi);
  vr = cp*vr + sp*pi;
  vi = cp*vi - sp*pr;
}

template<int T>
__device__ __forceinline__ void crx_7l_g(v2f& vr, v2f& vi,
                                         float ct, float st, int idx, float sg) {
  float c = rdlane(ct, idx), s = sg * rdlane(st, idx);
  constexpr int LT = 1 << (5 - T);
  float pr = lane_partner<LT>(vr.y);
  float pi = lane_partner<LT>(vi.y);
  vr.y = c*vr.y + s*pi;
  vi.y = c*vi.y - s*pr;
}

template<int C>
__device__ __forceinline__ void crx_l7_g(v2f& vr, v2f& vi, int lane,
                                         float ct, float st, int idx, float sg) {
  float c = rdlane(ct, idx), s = sg * rdlane(st, idx);
  constexpr int LC = 1 << (5 - C);
  const bool act = (lane & LC) != 0;
  const float cp = act ? c : 1.f, sp = act ? s : 0.f;
  float xr = vr.x, xi = vi.x, yr = vr.y, yi = vi.y;
  vr.x = cp*xr + sp*yi;  vi.x = cp*xi - sp*yr;
  vr.y = cp*yr + sp*xi;  vi.y = cp*yi - sp*xr;
}

template<int C>
__device__ __forceinline__ void crx_l6_g(v2f& vr, v2f& vi, int wv, int lane,
                                         float ct, float st, int idx, float sg, int site) {
  float c = rdlane(ct, idx), s = sg * rdlane(st, idx);
  float4 P = wexch(site, wv, lane, vr, vi);
  constexpr int LC = 1 << (5 - C);
  const bool act = (lane & LC) != 0;
  const float cp = act ? c : 1.f, sp = act ? s : 0.f;
  v2f Pr = {P.x, P.y}, Pi = {P.z, P.w};
  vr = cp*vr + sp*Pi;
  vi = cp*vi - sp*Pr;
}

__device__ __forceinline__ void crx_67_g(v2f& vr, v2f& vi, int h,
                                         float ct, float st, int idx, float sg) {
  if (h) {
    float c = rdlane(ct, idx), s = sg * rdlane(st, idx);
    float xr = vr.x, xi = vi.x, yr = vr.y, yi = vi.y;
    vr.x = c*xr + s*yi;  vi.x = c*xi - s*yr;
    vr.y = c*yr + s*xi;  vi.y = c*yi - s*xr;
  }
}

template<int T>
__device__ __forceinline__ void crx_6l_g(v2f& vr, v2f& vi, int h,
                                         float ct, float st, int idx, float sg) {
  if (h) {
    float c = rdlane(ct, idx), s = sg * rdlane(st, idx);
    constexpr int LT = 1 << (5 - T);
    v2f pr = lane_partner2<LT>(vr);
    v2f pi = lane_partner2<LT>(vi);
    vr = c*vr + s*pi;
    vi = c*vi - s*pr;
  }
}

// Fused RY(w6,ia) -> RY(w7,ib) -> CRX(7,6;ic): ONE exchange instead of two.
__device__ __forceinline__ void trio_fwd(v2f& vr, v2f& vi, int wv, int lane, int h,
                                         float ct, float st, int ia, int ib, int ic,
                                         float sg, int site) {
  float ca = rdlane(ct, ia), sa = sg * rdlane(st, ia);
  float cb = rdlane(ct, ib), sb = sg * rdlane(st, ib);
  float cc = rdlane(ct, ic), sc = sg * rdlane(st, ic);
  float4 P = wexch(site, wv, lane, vr, vi);   // partner (h^1): x=pr0 y=pr1 z=pi0 w=pi1
  const float lsa = h ? sa : -sa;
  v2f Pr = {P.x, P.y}, Pi = {P.z, P.w};
  // RY6 (packed): own' = ca*own + lsa*par ; par' = ca*par - lsa*own
  v2f bor = ca*vr + lsa*Pr, boi = ca*vi + lsa*Pi;
  v2f bpr = ca*Pr - lsa*vr, bpi = ca*Pi - lsa*vi;
  // RY7 on regs (cross-component)
  float cor0 = cb*bor.x - sb*bor.y, coi0 = cb*boi.x - sb*boi.y;
  float cor1 = sb*bor.x + cb*bor.y, coi1 = sb*boi.x + cb*boi.y;
  float cpr1 = sb*bpr.x + cb*bpr.y, cpi1 = sb*bpi.x + cb*bpi.y;
  // CRX(ctrl w7=r1, tgt w6)
  vr.x = cor0;               vi.x = coi0;
  vr.y = cc*cor1 + sc*cpi1;  vi.y = cc*coi1 - sc*cpr1;
}

// Adjoint mirror: CRX(7,6;ic) -> RY(w7,ib) -> RY(w6,ia), sg=-1 folded in.
__device__ __forceinline__ void trio_adj(v2f& vr, v2f& vi, int wv, int lane, int h,
                                         float ct, float st, int ia, int ib, int ic,
                                         float sg, int site) {
  float ca = rdlane(ct, ia), sa = sg * rdlane(st, ia);
  float cb = rdlane(ct, ib), sb = sg * rdlane(st, ib);
  float cc = rdlane(ct, ic), sc = sg * rdlane(st, ic);
  float4 P = wexch(site, wv, lane, vr, vi);
  // CRX on r=1 for own and partner
  float dor1 = cc*vr.y + sc*P.w,   doi1 = cc*vi.y - sc*P.y;
  float dpr1 = cc*P.y + sc*vi.y,   dpi1 = cc*P.w - sc*vr.y;
  // RY7 on regs
  float eor0 = cb*vr.x - sb*dor1,  eoi0 = cb*vi.x - sb*doi1;
  float eor1 = sb*vr.x + cb*dor1,  eoi1 = sb*vi.x + cb*doi1;
  float epr0 = cb*P.x  - sb*dpr1,  epi0 = cb*P.z  - sb*dpi1;
  float epr1 = sb*P.x  + cb*dpr1,  epi1 = sb*P.z  + cb*dpi1;
  // RY6 across wave pair (packed)
  const float lsa = h ? sa : -sa;
  v2f Eor = {eor0, eor1}, Eoi = {eoi0, eoi1};
  v2f Epr = {epr0, epr1}, Epi = {epi0, epi1};
  vr = ca*Eor + lsa*Epr;
  vi = ca*Eoi + lsa*Epi;
}

// ---------------- sim14 layers: ONE code copy each (noinline) ----------------
// 3 exchange sites per pass.

__device__ __noinline__ S4 sim14_fwd(S4 v, float ct, float st, int off, int site0) {
  const int tid = threadIdx.x;
  const int lane = tid & 63, wv = tid >> 6, h = wv >> 2;
  v2f vr = {v.r0, v.r1}, vi = {v.i0, v.i1};
  const float sg = 1.f;
  ry_lane_g<0>(vr,vi,lane,ct,st,off+0,sg); ry_lane_g<1>(vr,vi,lane,ct,st,off+1,sg);
  ry_lane_g<2>(vr,vi,lane,ct,st,off+2,sg); ry_lane_g<3>(vr,vi,lane,ct,st,off+3,sg);
  ry_lane_g<4>(vr,vi,lane,ct,st,off+4,sg); ry_lane_g<5>(vr,vi,lane,ct,st,off+5,sg);
  ry_wave6_g(vr,vi,wv,lane,h,ct,st,off+6,sg,site0+0);
  ry_reg7_g(vr,vi,ct,st,off+7,sg);
  crx_7l_g<0>(vr,vi,ct,st,off+8,sg);
  crx_67_g(vr,vi,h,ct,st,off+9,sg);
  crx_l6_g<5>(vr,vi,wv,lane,ct,st,off+10,sg,site0+1);
  crx_ll_g<4,5>(vr,vi,lane,ct,st,off+11,sg); crx_ll_g<3,4>(vr,vi,lane,ct,st,off+12,sg);
  crx_ll_g<2,3>(vr,vi,lane,ct,st,off+13,sg); crx_ll_g<1,2>(vr,vi,lane,ct,st,off+14,sg);
  crx_ll_g<0,1>(vr,vi,lane,ct,st,off+15,sg);
  ry_lane_g<0>(vr,vi,lane,ct,st,off+16,sg); ry_lane_g<1>(vr,vi,lane,ct,st,off+17,sg);
  ry_lane_g<2>(vr,vi,lane,ct,st,off+18,sg); ry_lane_g<3>(vr,vi,lane,ct,st,off+19,sg);
  ry_lane_g<4>(vr,vi,lane,ct,st,off+20,sg); ry_lane_g<5>(vr,vi,lane,ct,st,off+21,sg);
  trio_fwd(vr,vi,wv,lane,h,ct,st,off+22,off+23,off+24,sg,site0+2);
  crx_l7_g<0>(vr,vi,lane,ct,st,off+25,sg);
  crx_ll_g<1,0>(vr,vi,lane,ct,st,off+26,sg); crx_ll_g<2,1>(vr,vi,lane,ct,st,off+27,sg);
  crx_ll_g<3,2>(vr,vi,lane,ct,st,off+28,sg); crx_ll_g<4,3>(vr,vi,lane,ct,st,off+29,sg);
  crx_ll_g<5,4>(vr,vi,lane,ct,st,off+30,sg);
  crx_6l_g<5>(vr,vi,h,ct,st,off+31,sg);
  return {vr.x, vr.y, vi.x, vi.y};
}

__device__ __noinline__ S4 sim14_adj(S4 v, float ct, float st, int off, int site0) {
  const int tid = threadIdx.x;
  const int lane = tid & 63, wv = tid >> 6, h = wv >> 2;
  v2f vr = {v.r0, v.r1}, vi = {v.i0, v.i1};
  const float sg = -1.f;
  crx_6l_g<5>(vr,vi,h,ct,st,off+31,sg);
  crx_ll_g<5,4>(vr,vi,lane,ct,st,off+30,sg); crx_ll_g<4,3>(vr,vi,lane,ct,st,off+29,sg);
  crx_ll_g<3,2>(vr,vi,lane,ct,st,off+28,sg); crx_ll_g<2,1>(vr,vi,lane,ct,st,off+27,sg);
  crx_ll_g<1,0>(vr,vi,lane,ct,st,off+26,sg);
  crx_l7_g<0>(vr,vi,lane,ct,st,off+25,sg);
  trio_adj(vr,vi,wv,lane,h,ct,st,off+22,off+23,off+24,sg,site0+0);
  ry_lane_g<5>(vr,vi,lane,ct,st,off+21,sg); ry_lane_g<4>(vr,vi,lane,ct,st,off+20,sg);
  ry_lane_g<3>(vr,vi,lane,ct,st,off+19,sg); ry_lane_g<2>(vr,vi,lane,ct,st,off+18,sg);
  ry_lane_g<1>(vr,vi,lane,ct,st,off+17,sg); ry_lane_g<0>(vr,vi,lane,ct,st,off+16,sg);
  crx_ll_g<0,1>(vr,vi,lane,ct,st,off+15,sg); crx_ll_g<1,2>(vr,vi,lane,ct,st,off+14,sg);
  crx_ll_g<2,3>(vr,vi,lane,ct,st,off+13,sg); crx_ll_g<3,4>(vr,vi,lane,ct,st,off+12,sg);
  crx_ll_g<4,5>(vr,vi,lane,ct,st,off+11,sg);
  crx_l6_g<5>(vr,vi,wv,lane,ct,st,off+10,sg,site0+1);
  crx_67_g(vr,vi,h,ct,st,off+9,sg);
  crx_7l_g<0>(vr,vi,ct,st,off+8,sg);
  ry_reg7_g(vr,vi,ct,st,off+7,sg);
  ry_wave6_g(vr,vi,wv,lane,h,ct,st,off+6,sg,site0+2);
  ry_lane_g<5>(vr,vi,lane,ct,st,off+5,sg); ry_lane_g<4>(vr,vi,lane,ct,st,off+4,sg);
  ry_lane_g<3>(vr,vi,lane,ct,st,off+3,sg); ry_lane_g<2>(vr,vi,lane,ct,st,off+2,sg);
  ry_lane_g<1>(vr,vi,lane,ct,st,off+1,sg); ry_lane_g<0>(vr,vi,lane,ct,st,off+0,sg);
  return {vr.x, vr.y, vi.x, vi.y};
}

// ---------------- cooperative-row MLP layer (8 waves share rows) ----------------
// MODE: 0 = silu->yl, 1 = raw->yl, 2 = seltab ((float2*)yl)

template<int IN, int NP, int MODE>
__device__ __forceinline__ void mlp_layer(const float* __restrict__ W,
    const float* __restrict__ bias, const float* xl, float* yl,
    int rbase, int lane)
{
  const int sub = lane & 7;
  const int g   = lane >> 3;
#pragma unroll
  for (int p = 0; p < NP; ++p) {
    const int row = rbase + p * 8 + g;
    const float4* w4 = (const float4*)(W + row * IN) + sub;
    const float4* x4 = (const float4*)xl + sub;
    float acc = 0.f;
#pragma unroll
    for (int it = 0; it < IN / 32; ++it) {
      float4 w = w4[it * 8], e = x4[it * 8];
      acc += w.x*e.x + w.y*e.y + w.z*e.z + w.w*e.w;
    }
    acc = xor_sum<1>(acc);
    acc = xor_sum<2>(acc);
    acc = xor_sum<4>(acc);
    if (sub == 0) {
      float a = acc + bias[row];
      if constexpr (MODE == 0) {
        yl[row] = a / (1.f + __expf(-a));
      } else if constexpr (MODE == 1) {
        yl[row] = a;
      } else {
        float th = PI_F / (1.f + __expf(-a));   // theta/2 = pi * sigmoid(a)
        float sn, cn;
        __sincosf(th, &sn, &cn);
        ((float2*)yl)[row] = make_float2(cn, sn);
      }
    }
  }
}

// ---------------- main kernel: 512 threads = 8 waves, one batch elem/block ----------------

__global__ __launch_bounds__(512) void qsvt_kernel(
    const float* __restrict__ z_t, const float* __restrict__ t,
    const float* __restrict__ te_w1, const float* __restrict__ te_b1,
    const float* __restrict__ te_w2, const float* __restrict__ te_b2,
    const float* __restrict__ ip_w1, const float* __restrict__ ip_b1,
    const float* __restrict__ ip_w2, const float* __restrict__ ip_b2,
    const float* __restrict__ prep_p, const float* __restrict__ sig,
    const float* __restrict__ qff,
    const float* __restrict__ A_obs, const float* __restrict__ B_obs,
    const float* __restrict__ D_obs,
    const float* __restrict__ head_w, const float* __restrict__ head_b,
    float* __restrict__ out)
{
  __shared__ __align__(16) float emb[128];
  __shared__ __align__(16) float y1[128];
  __shared__ __align__(16) float hbuf[256];
  __shared__ __align__(16) float h1[256];
  __shared__ __align__(16) float2 seltab[256];   // [s*64+g] -> (cos(th/2), sin(th/2))
  __shared__ __align__(16) float2 qtab2[32];
  __shared__ __align__(16) float2 sX1[16], sX2[16], sF[16], sa0[4];
  __shared__ __align__(16) float dumpR[4][256];
  __shared__ __align__(16) float dumpI[4][256];
  __shared__ float redbuf[NOBS][4];
  __shared__ float hdc[NOBS][3], hxc[NOBS][6], hyc[NOBS][6];
  __shared__ __align__(16) float shw[128 * NOBS];
  __shared__ __align__(16) float shb[128];
  extern __shared__ float4 dxw[];                // 2 x 512 exchange buffers

  const int tid  = threadIdx.x;
  const int lane = tid & 63;
  const int wv   = tid >> 6;   // 0..7
  const int s    = wv & 3;     // ancilla value
  const int h    = wv >> 2;    // wire-6 value
  const int b    = blockIdx.x;

  // ===== Phase 0: wave 0 builds block-invariant ancilla matrices into LDS =====
  if (tid < 32) {
    float sn, cn;
    __sincosf(0.5f * qff[tid], &sn, &cn);
    qtab2[tid] = make_float2(cn, sn);
  }
  if (wv == 0) {
    float2 Ga[2][2][2], Gb[2][2][2];
    for (int ly = 0; ly < 2; ++ly)
      for (int qi = 0; qi < 2; ++qi) {
        float y = prep_p[ly*4 + qi*2 + 0], z = prep_p[ly*4 + qi*2 + 1];
        float cy, sy, cz, sz;
        __sincosf(0.5f*y, &sy, &cy);
        __sincosf(0.5f*z, &sz, &cz);
        float2 g00 = make_float2( cy*cz, -cy*sz);
        float2 g01 = make_float2(-sy*cz,  sy*sz);
        float2 g10 = make_float2( sy*cz,  sy*sz);
        float2 g11 = make_float2( cy*cz,  cy*sz);
        if (qi == 0) { Ga[ly][0][0]=g00; Ga[ly][0][1]=g01; Ga[ly][1][0]=g10; Ga[ly][1][1]=g11; }
        else         { Gb[ly][0][0]=g00; Gb[ly][0][1]=g01; Gb[ly][1][0]=g10; Gb[ly][1][1]=g11; }
      }
    float2 M[2][4][4];
    for (int ly = 0; ly < 2; ++ly) {
      float2 T[4][4];
      for (int i = 0; i < 4; ++i)
        for (int j = 0; j < 4; ++j)
          T[i][j] = cmul(Ga[ly][i>>1][j>>1], Gb[ly][i&1][j&1]);
      for (int j = 0; j < 4; ++j) {
        M[ly][0][j] = T[0][j]; M[ly][1][j] = T[1][j];
        M[ly][2][j] = T[3][j]; M[ly][3][j] = T[2][j];
      }
    }
    float2 U[4][4];
    for (int i = 0; i < 4; ++i)
      for (int j = 0; j < 4; ++j) {
        float2 acc = make_float2(0.f, 0.f);
        for (int kk = 0; kk < 4; ++kk) acc = cadd(acc, cmul(M[1][i][kk], M[0][kk][j]));
        U[i][j] = acc;
      }
    float c0n, s0n, c1, s1v, c2, s2v, c3, s3v;
    __sincosf(sig[0], &s0n, &c0n);
    __sincosf(sig[1], &s1v, &c1);
    __sincosf(sig[2], &s2v, &c2);
    __sincosf(sig[3], &s3v, &c3);
    if (lane < 16) {
      int i = lane >> 2, j = lane & 3;   // i = s (row), j = sp (col)
      float2 a1 = make_float2(0.f, 0.f), a2 = make_float2(0.f, 0.f);
      for (int k = 0; k < 4; ++k) {
        float2 tt = cmulc(U[i][k], U[j][k]);
        float sk = (k == 0) ? 1.f : -1.f;
        a1 = cadd(a1, cmul(tt, make_float2(c1, sk*s1v)));
        a2 = cadd(a2, cmul(tt, make_float2(c2, sk*s2v)));
      }
      sX1[lane] = a1;
      sX2[lane] = a2;
      float2 d3 = make_float2(c3, (i == 0) ? s3v : -s3v);
      sF[lane] = cmul(d3, make_float2(U[j][i].x, -U[j][i].y));
    }
    if (lane < 4) sa0[lane] = cmul(U[lane][0], make_float2(c0n, s0n));
  }

  // ===== Phase A: MLP (cooperative rows, 8 waves) =====
  if (tid < 128) {
    float fr = __expf(-9.210340371976184f * (float)(tid & 63) / 64.f);
    float arg = t[b] * fr;
    float sn, cn;
    __sincosf(arg, &sn, &cn);
    emb[tid] = (tid < 64) ? cn : sn;
  }
  __syncthreads();

  mlp_layer<128, 2, 0>(te_w1, te_b1, emb, y1, wv * 16, lane);
  if (tid < 128) hbuf[tid] = z_t[b * 128 + tid];
  __syncthreads();

  mlp_layer<128, 2, 1>(te_w2, te_b2, y1, hbuf + 128, wv * 16, lane);
  __syncthreads();

  mlp_layer<256, 4, 0>(ip_w1, ip_b1, hbuf, h1, wv * 32, lane);
  __syncthreads();

  mlp_layer<256, 4, 2>(ip_w2, ip_b2, h1, (float*)seltab, wv * 32, lane);

  // prefetch observable + head coefficients into LDS (off the tail path)
  if (tid < NOBS * 6)      { hxc[tid/6][tid%6] = A_obs[tid]; hyc[tid/6][tid%6] = B_obs[tid]; }
  else if (tid >= 64 && tid < 64 + NOBS*3) { int q = tid - 64; hdc[q/3][q%3] = 2.f * D_obs[(q/3)*4 + (q%3) + 1]; }
#pragma unroll
  for (int i = tid; i < 128*NOBS; i += 512) shw[i] = head_w[i];
  if (tid < 128) shb[tid] = head_b[tid];
  __syncthreads();  // seltab/coefs/matrices visible to all waves

  // per-wave angle tables in registers (lane g <-> gate g)
  float2 mycs = seltab[(s << 6) | lane];
  float selc = mycs.x, sels = mycs.y;
  float2 myq = qtab2[lane & 31];
  float qc = myq.x, qs = myq.y;

  // ===== Phase C: circuit. init = U*D0*|0..0> : only m=0 (lane0,h0,r0) nonzero =====
  S4 v;
  v.r0 = 0.f; v.r1 = 0.f; v.i0 = 0.f; v.i1 = 0.f;
  if (lane == 0 && h == 0) {
    float2 a0 = sa0[s];
    v.r0 = a0.x; v.i0 = a0.y;
  }

  // ancilla mix through the parity-alternating exchange buffer (1 barrier)
  auto ancmix = [&](const float2* R, int site) {
    float4* buf = dxw + (site & 1) * 512;
    buf[wv * 64 + lane] = make_float4(v.r0, v.r1, v.i0, v.i1);
    __syncthreads();
    float2 o0 = make_float2(0.f, 0.f), o1 = make_float2(0.f, 0.f);
#pragma unroll
    for (int sp = 0; sp < 4; ++sp) {
      float4 P = buf[(h * 4 + sp) * 64 + lane];
      float2 Rr = R[sp];
      o0 = cadd(o0, cmul(Rr, make_float2(P.x, P.z)));
      o1 = cadd(o1, cmul(Rr, make_float2(P.y, P.w)));
    }
    v.r0 = o0.x; v.i0 = o0.y; v.r1 = o1.x; v.i1 = o1.y;
  };

  // sites: 3 per sim14 pass, 1 per ancilla mix, strictly sequential
  v = sim14_fwd(v, selc, sels, 0, 0);
  v = sim14_fwd(v, selc, sels, 32, 3);
  ancmix(&sX1[s << 2], 6);
  v = sim14_adj(v, selc, sels, 32, 7);
  v = sim14_adj(v, selc, sels, 0, 10);
  ancmix(&sX2[s << 2], 13);
  v = sim14_fwd(v, selc, sels, 0, 14);
  v = sim14_fwd(v, selc, sels, 32, 17);
  ancmix(&sF[s << 2], 20);
  v = sim14_fwd(v, qc, qs, 0, 21);

  // ===== Phase D: dump state, observables =====
  *(float2*)&dumpR[s][(lane << 2) | (h << 1)] = make_float2(v.r0, v.r1);
  *(float2*)&dumpI[s][(lane << 2) | (h << 1)] = make_float2(v.i0, v.i1);
  __syncthreads();  // obs reads cross h

  // h=0 waves: w 0..3 ; h=1 waves: w 4..6
  const int w0 = h ? 4 : 0, w1 = h ? NOBS : 4;
  for (int w = w0; w < w1; ++w) {
    const int pb = 6 - w;  // wires (w, w+1) -> bits (7-w, 6-w) of m
    int g = lane;
    int ib = ((g >> pb) << (pb + 2)) | (g & ((1 << pb) - 1));
    float xr[4], xi[4];
#pragma unroll
    for (int i = 0; i < 4; ++i) { xr[i] = dumpR[s][ib + (i << pb)]; xi[i] = dumpI[s][ib + (i << pb)]; }
    float a = hdc[w][0] * (xr[0]*xr[0] + xi[0]*xi[0])
            + hdc[w][1] * (xr[1]*xr[1] + xi[1]*xi[1])
            + hdc[w][2] * (xr[2]*xr[2] + xi[2]*xi[2]);
    const int oi[6] = {1, 2, 2, 3, 3, 3};
    const int oj[6] = {0, 0, 1, 0, 1, 2};
#pragma unroll
    for (int k2 = 0; k2 < 6; ++k2) {
      int i = oi[k2], j = oj[k2];
      float rr = xr[i]*xr[j] + xi[i]*xi[j];   // Re(conj(v_i) v_j)
      float ii = xr[i]*xi[j] - xi[i]*xr[j];   // Im(conj(v_i) v_j)
      a += 2.f * (hxc[w][k2]*rr - hyc[w][k2]*ii);
    }
    a = xor_sum<32>(a);
    a = xor_sum<16>(a);
    a = xor_sum<8>(a);
    a = xor_sum<4>(a);
    a = xor_sum<2>(a);
    a = xor_sum<1>(a);
    if (lane == 0) redbuf[w][s] = a;
  }
  __syncthreads();

  // ===== Phase E: head =====
  if (tid < 128) {
    float acc = shb[tid];
#pragma unroll
    for (int w = 0; w < NOBS; ++w) {
      float ev = redbuf[w][0] + redbuf[w][1] + redbuf[w][2] + redbuf[w][3];
      acc += ev * shw[tid*NOBS + w];
    }
    out[b * 128 + tid] = acc;
  }
}

extern "C" void kernel_launch(void* const* d_in, const int* in_sizes, int n_in,
                              void* d_out, int out_size, void* d_ws, size_t ws_size,
                              hipStream_t stream) {
  (void)n_in; (void)out_size; (void)d_ws; (void)ws_size;
  const float* z_t    = (const float*)d_in[0];
  const float* t      = (const float*)d_in[1];
  const float* te_w1  = (const float*)d_in[2];
  const float* te_b1  = (const float*)d_in[3];
  const float* te_w2  = (const float*)d_in[4];
  const float* te_b2  = (const float*)d_in[5];
  const float* ip_w1  = (const float*)d_in[6];
  const float* ip_b1  = (const float*)d_in[7];
  const float* ip_w2  = (const float*)d_in[8];
  const float* ip_b2  = (const float*)d_in[9];
  const float* prep_p = (const float*)d_in[10];
  const float* sig    = (const float*)d_in[11];
  const float* qff    = (const float*)d_in[12];
  const float* A_obs  = (const float*)d_in[13];
  const float* B_obs  = (const float*)d_in[14];
  const float* D_obs  = (const float*)d_in[15];
  const float* head_w = (const float*)d_in[16];
  const float* head_b = (const float*)d_in[17];
  float* out = (float*)d_out;

  int B = in_sizes[1];  // t is (B,)
  size_t dyn = 2 * 512 * sizeof(float4);
  qsvt_kernel<<<B, 512, dyn, stream>>>(
      z_t, t, te_w1, te_b1, te_w2, te_b2, ip_w1, ip_b1, ip_w2, ip_b2,
      prep_p, sig, qff, A_obs, B_obs, D_obs, head_w, head_b, out);
}